// Round 6
// baseline (287.504 us; speedup 1.0000x reference)
//
#include <hip/hip_runtime.h>
#include <hip/hip_bf16.h>

#define SEQ 2048
#define DMODEL 1024
#define NHEAD 16
#define HDIM 64
#define DPOS 64
#define BATCH 2

constexpr float EVENT_HORIZON = 1e-6f;
constexpr float MAX_FORCE = 50.0f;
constexpr float CURV = 0.15f;
constexpr float SHIFT = 40.0f;   // softmax shift: exp(min(f,50)-40) <= e^10, fp16-safe

typedef __attribute__((ext_vector_type(8))) short frag8;        // 8 bf16/ushort
typedef __attribute__((ext_vector_type(8))) _Float16 half8;     // 8 fp16 (4 VGPRs)
typedef __attribute__((ext_vector_type(4))) float frag4f;       // 4 fp32 (C/D)

__device__ inline short bfbits(float f) {
  __hip_bfloat16 h = __float2bfloat16(f);
  return *reinterpret_cast<short*>(&h);
}
__device__ inline float bf2f(unsigned short u) {
  unsigned v = ((unsigned)u) << 16;
  union { unsigned u; float f; } c; c.u = v; return c.f;
}

// ---------------------------------------------------------------------------
// Prep A: transpose x -> xt[bh][d][j] fp16. Lane = d (coalesced reads),
// each thread writes one contiguous half8 (16 B).
// ---------------------------------------------------------------------------
__global__ __launch_bounds__(256) void prep_xt(
    const float* __restrict__ x, _Float16* __restrict__ xt) {
  int bh = blockIdx.x;           // b*16+h
  int h = bh & 15, b = bh >> 4;
  int t = threadIdx.x;
  int d = t & 63;
  int jg = (t >> 6) + (blockIdx.y << 2);   // j-group of 8, 0..255
  int j0 = jg * 8;
  const float* src = x + (size_t)(b * SEQ) * DMODEL + h * HDIM + d;
  half8 v;
#pragma unroll
  for (int jj = 0; jj < 8; ++jj)
    v[jj] = (_Float16)src[(size_t)(j0 + jj) * DMODEL];
  *(half8*)(xt + ((size_t)bh * HDIM + d) * SEQ + j0) = v;
}

// ---------------------------------------------------------------------------
// Prep B: Wout fp32 -> fp16 straight convert.
// ---------------------------------------------------------------------------
__global__ __launch_bounds__(256) void prep_wh(
    const float* __restrict__ Wout, _Float16* __restrict__ wh) {
  int i = blockIdx.x * 256 + threadIdx.x;
  float4 v = ((const float4*)Wout)[i];
  _Float16 o[4] = {(_Float16)v.x, (_Float16)v.y, (_Float16)v.z, (_Float16)v.w};
  *(float2*)(wh + 4 * (size_t)i) = *(float2*)o;
}

// ---------------------------------------------------------------------------
// Kernel 1: masses[bh][s] = softplus( dot(x[b,s,h*64:+64], W_mass[h,:]) )
// ---------------------------------------------------------------------------
__global__ __launch_bounds__(256) void masses_kernel(
    const float* __restrict__ x, const float* __restrict__ Wm,
    float* __restrict__ masses) {
  int n = blockIdx.x * blockDim.x + threadIdx.x;
  if (n >= BATCH * NHEAD * SEQ) return;
  int s  = n & (SEQ - 1);
  int bh = n >> 11;
  int h  = bh & (NHEAD - 1);
  int b  = bh >> 4;
  const float* xp = x + ((size_t)(b * SEQ + s)) * DMODEL + h * HDIM;
  const float* wp = Wm + h * HDIM;
  float acc = 0.f;
#pragma unroll
  for (int d = 0; d < HDIM; ++d) acc += xp[d] * wp[d];
  masses[n] = (acc > 20.f) ? acc : log1pf(expf(acc));
}

// ---------------------------------------------------------------------------
// Kernel 2: LDS-tiled distance kernel, bf16 output (bf16 handles invd up to
// 1e6 on the diagonal; diagonal force clamps to 50 regardless).
// ---------------------------------------------------------------------------
__global__ __launch_bounds__(256) void invdist_kernel(
    const float* __restrict__ pos, unsigned short* __restrict__ invd) {
  __shared__ float Li[64 * 68];
  __shared__ float Lj[64 * 68];
  int t = threadIdx.x;
  int i0 = blockIdx.y * 64, j0 = blockIdx.x * 64;

  int kk = (t & 15) * 4;
  int rr = t >> 4;
#pragma unroll
  for (int q = 0; q < 4; ++q) {
    int row = q * 16 + rr;
    float4 a = *(const float4*)(pos + (size_t)(i0 + row) * DPOS + kk);
    float4 b = *(const float4*)(pos + (size_t)(j0 + row) * DPOS + kk);
    Li[(kk + 0) * 68 + row] = a.x; Li[(kk + 1) * 68 + row] = a.y;
    Li[(kk + 2) * 68 + row] = a.z; Li[(kk + 3) * 68 + row] = a.w;
    Lj[(kk + 0) * 68 + row] = b.x; Lj[(kk + 1) * 68 + row] = b.y;
    Lj[(kk + 2) * 68 + row] = b.z; Lj[(kk + 3) * 68 + row] = b.w;
  }
  __syncthreads();

  int ti = (t >> 4) * 4;
  int tj = (t & 15) * 4;

  float acc[4][4];
#pragma unroll
  for (int a = 0; a < 4; ++a)
#pragma unroll
    for (int b = 0; b < 4; ++b) acc[a][b] = 0.f;

#pragma unroll 8
  for (int k = 0; k < 64; ++k) {
    float4 a = *(const float4*)(&Li[k * 68 + ti]);
    float4 b = *(const float4*)(&Lj[k * 68 + tj]);
    float av[4] = {a.x, a.y, a.z, a.w};
    float bv[4] = {b.x, b.y, b.z, b.w};
#pragma unroll
    for (int mi = 0; mi < 4; ++mi)
#pragma unroll
      for (int mj = 0; mj < 4; ++mj) {
        float d = av[mi] - bv[mj];
        acc[mi][mj] += d * d;
      }
  }

#pragma unroll
  for (int mi = 0; mi < 4; ++mi) {
    ushort4 o;
    unsigned short* op = (unsigned short*)&o;
#pragma unroll
    for (int mj = 0; mj < 4; ++mj) {
      float d2 = acc[mi][mj];
      float dn = sqrtf(d2 + EVENT_HORIZON);
      float w = d2 * (1.f + CURV * __cosf(dn));
      op[mj] = (unsigned short)bfbits(1.0f / fmaxf(w, EVENT_HORIZON));
    }
    *(ushort4*)(&invd[(size_t)(i0 + ti + mi) * SEQ + j0 + tj]) = o;
  }
}

// ---------------------------------------------------------------------------
// Kernel 3: fused gravitational attention, fp16 MFMA PV, NO LDS, NO barriers.
// Block = 256 thr = 4 waves; wave = 16 i-rows of one head. B-frags are direct
// contiguous 16B loads from pre-transposed xt[bh][d][j].
// P = exp(min(f,50) - 40) in (0, e^10]; shift cancels in softmax ratio.
// grid: x = bh (32, fast dim -> same-i blocks share invd in L2), y = i/64.
// ---------------------------------------------------------------------------
__global__ __launch_bounds__(256) void attn_mfma_kernel(
    const _Float16* __restrict__ xt, const float* __restrict__ masses,
    const unsigned short* __restrict__ invd, const float* __restrict__ G,
    _Float16* __restrict__ attnout) {
  int bh = blockIdx.x;
  int h = bh & (NHEAD - 1), b = bh >> 4;
  int i0 = blockIdx.y * 64;
  int t = threadIdx.x;
  int w = t >> 6, lane = t & 63;
  int l15 = lane & 15, quad = lane >> 4;
  int iw = i0 + w * 16;

  float gabs = fabsf(G[h]);
  const float* mrow = masses + (size_t)bh * SEQ;
  float cm = gabs * mrow[iw + l15];                     // row scalar (m = l15)
  const unsigned short* ivrow = invd + (size_t)(iw + l15) * SEQ;
  const _Float16* vbase = xt + (size_t)bh * HDIM * SEQ; // [d][j]

  frag4f acc[4];
#pragma unroll
  for (int nt = 0; nt < 4; ++nt) acc[nt] = (frag4f)0.f;
  float sum = 0.f;

  for (int j0 = 0; j0 < SEQ; j0 += 64) {
#pragma unroll
    for (int kh = 0; kh < 2; ++kh) {
      int jb = j0 + kh * 32 + quad * 8;
      float4 m0 = *(const float4*)(mrow + jb);
      float4 m1 = *(const float4*)(mrow + jb + 4);
      float mj[8] = {m0.x, m0.y, m0.z, m0.w, m1.x, m1.y, m1.z, m1.w};
      frag8 ivv = *(const frag8*)(ivrow + jb);

      half8 A;
#pragma unroll
      for (int jj = 0; jj < 8; ++jj) {
        float iv = bf2f((unsigned short)ivv[jj]);
        float f = fmaf(cm * mj[jj], iv, -SHIFT);        // f - 40
        float e = __expf(fminf(f, MAX_FORCE - SHIFT));  // exp(min(f,50)-40)
        sum += e;
        A[jj] = (_Float16)e;
      }
#pragma unroll
      for (int nt = 0; nt < 4; ++nt) {
        half8 Bf = *(const half8*)(vbase + (size_t)(nt * 16 + l15) * SEQ + jb);
        acc[nt] = __builtin_amdgcn_mfma_f32_16x16x32_f16(A, Bf, acc[nt], 0, 0, 0);
      }
    }
  }

  // wave-reduce row sums (rows indexed by l15)
  sum += __shfl_xor(sum, 16, 64);
  sum += __shfl_xor(sum, 32, 64);

#pragma unroll
  for (int reg = 0; reg < 4; ++reg) {
    int r = quad * 4 + reg;            // C/D row within 16x16 tile
    float s = 1.f / __shfl(sum, r);
#pragma unroll
    for (int nt = 0; nt < 4; ++nt) {
      int dcol = h * HDIM + nt * 16 + l15;
      attnout[(size_t)(b * SEQ + iw + r) * DMODEL + dcol] =
          (_Float16)(acc[nt][reg] * s);
    }
  }
}

// ---------------------------------------------------------------------------
// Kernel 4: out = attnout @ wh^T via fp16 MFMA, 128x128 tile, K-chunk 32.
// 4 waves, each 64x64 (4x4 fragment grid). C[m][n] = sum_k A[m][k] W[n][k].
// ---------------------------------------------------------------------------
__global__ __launch_bounds__(256) void out_gemm_mfma(
    const _Float16* __restrict__ Ag, const _Float16* __restrict__ Wg,
    float* __restrict__ C) {
  __shared__ _Float16 As[128 * 40];   // [m][k], stride 40 fp16 (80 B)
  __shared__ _Float16 Bs[128 * 40];   // [n][k]

  int t = threadIdx.x;
  int w = t >> 6, lane = t & 63;
  int l15 = lane & 15, quad = lane >> 4;
  int m0 = blockIdx.y * 128;
  int n0 = blockIdx.x * 128;
  int mh = (w & 1) * 64;
  int nh = (w >> 1) * 64;

  int sr = t >> 1, skb = t & 1;   // staging: row 0..127, k-half of 16

  frag4f acc[4][4];
#pragma unroll
  for (int mt = 0; mt < 4; ++mt)
#pragma unroll
    for (int nt = 0; nt < 4; ++nt) acc[mt][nt] = (frag4f)0.f;

  for (int k0 = 0; k0 < DMODEL; k0 += 32) {
    const half8* ap = (const half8*)(Ag + (size_t)(m0 + sr) * DMODEL + k0 + skb * 16);
    half8 a0 = ap[0], a1 = ap[1];
    const half8* bp = (const half8*)(Wg + (size_t)(n0 + sr) * DMODEL + k0 + skb * 16);
    half8 b0 = bp[0], b1 = bp[1];

    __syncthreads();
    *(half8*)(&As[sr * 40 + skb * 16]) = a0;
    *(half8*)(&As[sr * 40 + skb * 16 + 8]) = a1;
    *(half8*)(&Bs[sr * 40 + skb * 16]) = b0;
    *(half8*)(&Bs[sr * 40 + skb * 16 + 8]) = b1;
    __syncthreads();

    half8 Af[4], Bf[4];
#pragma unroll
    for (int mt = 0; mt < 4; ++mt)
      Af[mt] = *(const half8*)(&As[(mh + mt * 16 + l15) * 40 + quad * 8]);
#pragma unroll
    for (int nt = 0; nt < 4; ++nt)
      Bf[nt] = *(const half8*)(&Bs[(nh + nt * 16 + l15) * 40 + quad * 8]);
#pragma unroll
    for (int mt = 0; mt < 4; ++mt)
#pragma unroll
      for (int nt = 0; nt < 4; ++nt)
        acc[mt][nt] = __builtin_amdgcn_mfma_f32_16x16x32_f16(Af[mt], Bf[nt], acc[mt][nt], 0, 0, 0);
  }

#pragma unroll
  for (int mt = 0; mt < 4; ++mt)
#pragma unroll
    for (int nt = 0; nt < 4; ++nt)
#pragma unroll
      for (int reg = 0; reg < 4; ++reg) {
        int m = m0 + mh + mt * 16 + quad * 4 + reg;
        int n = n0 + nh + nt * 16 + l15;
        C[(size_t)m * DMODEL + n] = acc[mt][nt][reg];
      }
}

// ---------------------------------------------------------------------------
extern "C" void kernel_launch(void* const* d_in, const int* in_sizes, int n_in,
                              void* d_out, int out_size, void* d_ws, size_t ws_size,
                              hipStream_t stream) {
  const float* x    = (const float*)d_in[0];
  const float* pos  = (const float*)d_in[1];
  const float* Wm   = (const float*)d_in[2];
  const float* G    = (const float*)d_in[3];
  const float* Wout = (const float*)d_in[4];
  float* out = (float*)d_out;

  // workspace layout (bytes)
  char* wsb = (char*)d_ws;
  float* masses = (float*)wsb;                                    // 256 KB
  unsigned short* invd = (unsigned short*)(wsb + (1 << 18));      // 8 MB
  _Float16* attnout = (_Float16*)(wsb + (1 << 18) + (8 << 20));   // 8 MB
  _Float16* xt      = (_Float16*)(wsb + (1 << 18) + (16 << 20));  // 8 MB
  _Float16* wh      = (_Float16*)(wsb + (1 << 18) + (24 << 20));  // 2 MB

  prep_xt<<<dim3(BATCH * NHEAD, 64), 256, 0, stream>>>(x, xt);
  prep_wh<<<(DMODEL * DMODEL / 4) / 256, 256, 0, stream>>>(Wout, wh);
  masses_kernel<<<(BATCH * NHEAD * SEQ) / 256, 256, 0, stream>>>(x, Wm, masses);
  invdist_kernel<<<dim3(SEQ / 64, SEQ / 64), 256, 0, stream>>>(pos, invd);
  attn_mfma_kernel<<<dim3(BATCH * NHEAD, SEQ / 64), 256, 0, stream>>>(
      xt, masses, invd, G, attnout);
  out_gemm_mfma<<<dim3(DMODEL / 128, (BATCH * SEQ) / 128), 256, 0, stream>>>(
      attnout, wh, out);
}

// Round 8
// 201.060 us; speedup vs baseline: 1.4299x; 1.4299x over previous
//
#include <hip/hip_runtime.h>
#include <hip/hip_bf16.h>

#define SEQ 2048
#define DMODEL 1024
#define NHEAD 16
#define HDIM 64
#define DPOS 64
#define BATCH 2

constexpr float EVENT_HORIZON = 1e-6f;
constexpr float MAX_FORCE = 50.0f;
constexpr float CURV = 0.15f;
constexpr float SHIFT = 40.0f;   // P = exp(min(f,50)-40) <= e^10: fp16-safe, ratio-invariant

typedef __attribute__((ext_vector_type(8))) short frag8;        // 8 bf16/ushort
typedef __attribute__((ext_vector_type(8))) _Float16 half8;     // 8 fp16
typedef __attribute__((ext_vector_type(2))) _Float16 half2t;    // 2 fp16
typedef __attribute__((ext_vector_type(4))) float frag4f;       // 4 fp32 (C/D)

union A8u { half8 v; half2t h[4]; };

__device__ inline short bfbits(float f) {
  __hip_bfloat16 h = __float2bfloat16(f);
  return *reinterpret_cast<short*>(&h);
}
__device__ inline float bf2f(unsigned short u) {
  unsigned v = ((unsigned)u) << 16;
  union { unsigned u; float f; } c; c.u = v; return c.f;
}
__device__ inline half2t pkrtz(float a, float b) {
  return __builtin_bit_cast(half2t, __builtin_amdgcn_cvt_pkrtz(a, b));
}
// XOR swizzle in 16B units: row = 8 units (128B) -> any 16-lane b128 access
// pattern (fixed unit, consecutive rows) covers all 32 banks <=2-way.
__device__ inline int swz(int row, int u) { return row * 8 + (u ^ (row & 7)); }

// ---------------------------------------------------------------------------
// Prep A: transpose x -> xt[bh][d][j] fp16.
// ---------------------------------------------------------------------------
__global__ __launch_bounds__(256) void prep_xt(
    const float* __restrict__ x, _Float16* __restrict__ xt) {
  int bh = blockIdx.x;           // b*16+h
  int h = bh & 15, b = bh >> 4;
  int t = threadIdx.x;
  int d = t & 63;
  int jg = (t >> 6) + (blockIdx.y << 2);   // j-group of 8, 0..255
  int j0 = jg * 8;
  const float* src = x + (size_t)(b * SEQ) * DMODEL + h * HDIM + d;
  half8 v;
#pragma unroll
  for (int jj = 0; jj < 8; ++jj)
    v[jj] = (_Float16)src[(size_t)(j0 + jj) * DMODEL];
  *(half8*)(xt + ((size_t)bh * HDIM + d) * SEQ + j0) = v;
}

// ---------------------------------------------------------------------------
// Prep B: Wout fp32 -> fp16.
// ---------------------------------------------------------------------------
__global__ __launch_bounds__(256) void prep_wh(
    const float* __restrict__ Wout, _Float16* __restrict__ wh) {
  int i = blockIdx.x * 256 + threadIdx.x;
  float4 v = ((const float4*)Wout)[i];
  _Float16 o[4] = {(_Float16)v.x, (_Float16)v.y, (_Float16)v.z, (_Float16)v.w};
  *(float2*)(wh + 4 * (size_t)i) = *(float2*)o;
}

// ---------------------------------------------------------------------------
// Kernel 1: masses[bh][s] = softplus( dot(x[b,s,h*64:+64], W_mass[h,:]) )
// ---------------------------------------------------------------------------
__global__ __launch_bounds__(256) void masses_kernel(
    const float* __restrict__ x, const float* __restrict__ Wm,
    float* __restrict__ masses) {
  int n = blockIdx.x * blockDim.x + threadIdx.x;
  if (n >= BATCH * NHEAD * SEQ) return;
  int s  = n & (SEQ - 1);
  int bh = n >> 11;
  int h  = bh & (NHEAD - 1);
  int b  = bh >> 4;
  const float* xp = x + ((size_t)(b * SEQ + s)) * DMODEL + h * HDIM;
  const float* wp = Wm + h * HDIM;
  float acc = 0.f;
#pragma unroll
  for (int d = 0; d < HDIM; ++d) acc += xp[d] * wp[d];
  masses[n] = (acc > 20.f) ? acc : log1pf(expf(acc));
}

// ---------------------------------------------------------------------------
// Kernel 2: LDS-tiled distance kernel, bf16 output (bf16 keeps the 1e6
// diagonal representable -> diagonal force clamps to exactly 50).
// ---------------------------------------------------------------------------
__global__ __launch_bounds__(256) void invdist_kernel(
    const float* __restrict__ pos, unsigned short* __restrict__ invd) {
  __shared__ float Li[64 * 68];
  __shared__ float Lj[64 * 68];
  int t = threadIdx.x;
  int i0 = blockIdx.y * 64, j0 = blockIdx.x * 64;

  int kk = (t & 15) * 4;
  int rr = t >> 4;
#pragma unroll
  for (int q = 0; q < 4; ++q) {
    int row = q * 16 + rr;
    float4 a = *(const float4*)(pos + (size_t)(i0 + row) * DPOS + kk);
    float4 b = *(const float4*)(pos + (size_t)(j0 + row) * DPOS + kk);
    Li[(kk + 0) * 68 + row] = a.x; Li[(kk + 1) * 68 + row] = a.y;
    Li[(kk + 2) * 68 + row] = a.z; Li[(kk + 3) * 68 + row] = a.w;
    Lj[(kk + 0) * 68 + row] = b.x; Lj[(kk + 1) * 68 + row] = b.y;
    Lj[(kk + 2) * 68 + row] = b.z; Lj[(kk + 3) * 68 + row] = b.w;
  }
  __syncthreads();

  int ti = (t >> 4) * 4;
  int tj = (t & 15) * 4;

  float acc[4][4];
#pragma unroll
  for (int a = 0; a < 4; ++a)
#pragma unroll
    for (int b = 0; b < 4; ++b) acc[a][b] = 0.f;

#pragma unroll 8
  for (int k = 0; k < 64; ++k) {
    float4 a = *(const float4*)(&Li[k * 68 + ti]);
    float4 b = *(const float4*)(&Lj[k * 68 + tj]);
    float av[4] = {a.x, a.y, a.z, a.w};
    float bv[4] = {b.x, b.y, b.z, b.w};
#pragma unroll
    for (int mi = 0; mi < 4; ++mi)
#pragma unroll
      for (int mj = 0; mj < 4; ++mj) {
        float d = av[mi] - bv[mj];
        acc[mi][mj] += d * d;
      }
  }

#pragma unroll
  for (int mi = 0; mi < 4; ++mi) {
    ushort4 o;
    unsigned short* op = (unsigned short*)&o;
#pragma unroll
    for (int mj = 0; mj < 4; ++mj) {
      float d2 = acc[mi][mj];
      float dn = sqrtf(d2 + EVENT_HORIZON);
      float w = d2 * (1.f + CURV * __cosf(dn));
      op[mj] = (unsigned short)bfbits(1.0f / fmaxf(w, EVENT_HORIZON));
    }
    *(ushort4*)(&invd[(size_t)(i0 + ti + mi) * SEQ + j0 + tj]) = o;
  }
}

// ---------------------------------------------------------------------------
// Kernel 3: fused gravitational attention, fp16 MFMA PV, swizzled LDS.
// Block = 256 = 4 waves = 2 i-tiles x 2 j-half streams.
//   wave w: it = w>>1 (16 i-rows), s = w&1 (j in [s*1024, s*1024+1024)).
// Streams share LDS V-chunks: waves (0,s),(1,s) stage+consume stream s.
// grid (32 bh, 64 i/32) = 2048 blocks -> 8 blocks/CU -> up to 8 waves/SIMD.
// Epilogue: j-half partials (acc + rowsum) combined through LDS.
// ---------------------------------------------------------------------------
__global__ __launch_bounds__(256, 6) void attn_mfma_kernel(
    const _Float16* __restrict__ xt, const float* __restrict__ masses,
    const unsigned short* __restrict__ invd, const float* __restrict__ G,
    _Float16* __restrict__ attnout) {
  __shared__ _Float16 Vs[2][64 * 64];   // 2 streams x 8 KB, XOR-swizzled

  int bh = blockIdx.x;
  int h = bh & (NHEAD - 1), b = bh >> 4;
  int ibase = blockIdx.y * 32;
  int t = threadIdx.x, w = t >> 6, lane = t & 63;
  int it = w >> 1, s = w & 1;
  int l15 = lane & 15, quad = lane >> 4;
  int iw = ibase + it * 16;

  float gabs = fabsf(G[h]);
  const float* mrow = masses + (size_t)bh * SEQ;
  float cm = gabs * mrow[iw + l15];                    // row scalar (i = iw+l15)
  const unsigned short* ivrow = invd + (size_t)(iw + l15) * SEQ + s * 1024;
  const float* mjb = mrow + s * 1024;

  // staging role within stream s (128 threads = waves {s, s+2}):
  int sid = it * 64 + lane;        // 0..127
  int srow = sid >> 1;             // d-row 0..63
  int sseg = (sid & 1) * 4;        // first 16B-unit (4 units each)
  const _Float16* srcrow =
      xt + ((size_t)bh * HDIM + srow) * SEQ + s * 1024 + sseg * 8;
  _Float16* myVs = Vs[s];

  frag4f acc[4];
#pragma unroll
  for (int nt = 0; nt < 4; ++nt) acc[nt] = (frag4f)0.f;
  float sum = 0.f;

  for (int c = 0; c < 16; ++c) {
    const _Float16* sp = srcrow + c * 64;
    half8 st0 = *(const half8*)(sp);
    half8 st1 = *(const half8*)(sp + 8);
    half8 st2 = *(const half8*)(sp + 16);
    half8 st3 = *(const half8*)(sp + 24);
    __syncthreads();  // previous chunk's reads done
    *(half8*)(myVs + swz(srow, sseg + 0) * 8) = st0;
    *(half8*)(myVs + swz(srow, sseg + 1) * 8) = st1;
    *(half8*)(myVs + swz(srow, sseg + 2) * 8) = st2;
    *(half8*)(myVs + swz(srow, sseg + 3) * 8) = st3;
    __syncthreads();  // writes visible

#pragma unroll
    for (int kh = 0; kh < 2; ++kh) {
      int jl = c * 64 + kh * 32 + quad * 8;
      float4 m0 = *(const float4*)(mjb + jl);
      float4 m1 = *(const float4*)(mjb + jl + 4);
      float mj[8] = {m0.x, m0.y, m0.z, m0.w, m1.x, m1.y, m1.z, m1.w};
      frag8 ivv = *(const frag8*)(ivrow + jl);

      float e[8];
#pragma unroll
      for (int jj = 0; jj < 8; ++jj) {
        float iv = bf2f((unsigned short)ivv[jj]);
        float f = fmaf(cm * mj[jj], iv, -SHIFT);
        e[jj] = __expf(fminf(f, MAX_FORCE - SHIFT));
        sum += e[jj];
      }
      A8u A;
#pragma unroll
      for (int p = 0; p < 4; ++p)
        A.h[p] = pkrtz(e[2 * p], e[2 * p + 1]);

#pragma unroll
      for (int nt = 0; nt < 4; ++nt) {
        half8 Bf = *(const half8*)(myVs + swz(nt * 16 + l15, kh * 4 + quad) * 8);
        acc[nt] = __builtin_amdgcn_mfma_f32_16x16x32_f16(A.v, Bf, acc[nt], 0, 0, 0);
      }
    }
  }

  // row sums: lane L -> total for row (L&15) of this j-half
  sum += __shfl_xor(sum, 16, 64);
  sum += __shfl_xor(sum, 32, 64);

  // combine the two j-halves through LDS (reuse Vs)
  float* fb = (float*)&Vs[0][0];
  __syncthreads();
  if (s == 1) {
#pragma unroll
    for (int nt = 0; nt < 4; ++nt)
#pragma unroll
      for (int reg = 0; reg < 4; ++reg)
        fb[it * 1088 + (quad * 4 + reg) * 64 + nt * 16 + l15] = acc[nt][reg];
    if (lane < 16) fb[it * 1088 + 1024 + lane] = sum;
  }
  __syncthreads();
  if (s == 0) {
#pragma unroll
    for (int reg = 0; reg < 4; ++reg) {
      int r = quad * 4 + reg;
      float stot = __shfl(sum, r) + fb[it * 1088 + 1024 + r];
      float inv = 1.f / stot;
#pragma unroll
      for (int nt = 0; nt < 4; ++nt) {
        float o = (acc[nt][reg] + fb[it * 1088 + r * 64 + nt * 16 + l15]) * inv;
        attnout[(size_t)(b * SEQ + iw + r) * DMODEL + h * HDIM + nt * 16 + l15] =
            (_Float16)o;
      }
    }
  }
}

// ---------------------------------------------------------------------------
// Kernel 4: out = attnout @ wh^T via fp16 MFMA. 64x64 tile, BK=64, swizzled
// LDS. 4 waves, each 32x32 (2x2 frags). grid (16,64) = 1024 blocks.
// ---------------------------------------------------------------------------
__global__ __launch_bounds__(256) void out_gemm_mfma(
    const _Float16* __restrict__ Ag, const _Float16* __restrict__ Wg,
    float* __restrict__ C) {
  __shared__ _Float16 As[64 * 64];
  __shared__ _Float16 Bs[64 * 64];

  int t = threadIdx.x, w = t >> 6, lane = t & 63;
  int l15 = lane & 15, quad = lane >> 4;
  int m0 = blockIdx.y * 64, n0 = blockIdx.x * 64;
  int mq = (w & 1) * 32, nq = (w >> 1) * 32;

  int srow = t >> 2;         // 0..63
  int su = (t & 3) * 2;      // units 0,2,4,6

  frag4f acc[2][2];
#pragma unroll
  for (int mt = 0; mt < 2; ++mt)
#pragma unroll
    for (int nt = 0; nt < 2; ++nt) acc[mt][nt] = (frag4f)0.f;

  for (int k0 = 0; k0 < DMODEL; k0 += 64) {
    const _Float16* ap = Ag + (size_t)(m0 + srow) * DMODEL + k0 + su * 8;
    const _Float16* bp = Wg + (size_t)(n0 + srow) * DMODEL + k0 + su * 8;
    half8 a0 = *(const half8*)(ap);
    half8 a1 = *(const half8*)(ap + 8);
    half8 b0 = *(const half8*)(bp);
    half8 b1 = *(const half8*)(bp + 8);

    __syncthreads();
    *(half8*)(As + swz(srow, su) * 8)     = a0;
    *(half8*)(As + swz(srow, su + 1) * 8) = a1;
    *(half8*)(Bs + swz(srow, su) * 8)     = b0;
    *(half8*)(Bs + swz(srow, su + 1) * 8) = b1;
    __syncthreads();

#pragma unroll
    for (int kh = 0; kh < 2; ++kh) {
      half8 Af[2], Bf[2];
#pragma unroll
      for (int mt = 0; mt < 2; ++mt)
        Af[mt] = *(const half8*)(As + swz(mq + mt * 16 + l15, kh * 4 + quad) * 8);
#pragma unroll
      for (int nt = 0; nt < 2; ++nt)
        Bf[nt] = *(const half8*)(Bs + swz(nq + nt * 16 + l15, kh * 4 + quad) * 8);
#pragma unroll
      for (int mt = 0; mt < 2; ++mt)
#pragma unroll
        for (int nt = 0; nt < 2; ++nt)
          acc[mt][nt] = __builtin_amdgcn_mfma_f32_16x16x32_f16(Af[mt], Bf[nt], acc[mt][nt], 0, 0, 0);
    }
  }

#pragma unroll
  for (int mt = 0; mt < 2; ++mt)
#pragma unroll
    for (int nt = 0; nt < 2; ++nt)
#pragma unroll
      for (int reg = 0; reg < 4; ++reg) {
        int m = m0 + mq + mt * 16 + quad * 4 + reg;
        int n = n0 + nq + nt * 16 + l15;
        C[(size_t)m * DMODEL + n] = acc[mt][nt][reg];
      }
}

// ---------------------------------------------------------------------------
extern "C" void kernel_launch(void* const* d_in, const int* in_sizes, int n_in,
                              void* d_out, int out_size, void* d_ws, size_t ws_size,
                              hipStream_t stream) {
  const float* x    = (const float*)d_in[0];
  const float* pos  = (const float*)d_in[1];
  const float* Wm   = (const float*)d_in[2];
  const float* G    = (const float*)d_in[3];
  const float* Wout = (const float*)d_in[4];
  float* out = (float*)d_out;

  char* wsb = (char*)d_ws;
  float* masses = (float*)wsb;                                    // 256 KB
  unsigned short* invd = (unsigned short*)(wsb + (1 << 18));      // 8 MB
  _Float16* attnout = (_Float16*)(wsb + (1 << 18) + (8 << 20));   // 8 MB
  _Float16* xt      = (_Float16*)(wsb + (1 << 18) + (16 << 20));  // 8 MB
  _Float16* wh      = (_Float16*)(wsb + (1 << 18) + (24 << 20));  // 2 MB

  prep_xt<<<dim3(BATCH * NHEAD, 64), 256, 0, stream>>>(x, xt);
  prep_wh<<<(DMODEL * DMODEL / 4) / 256, 256, 0, stream>>>(Wout, wh);
  masses_kernel<<<(BATCH * NHEAD * SEQ) / 256, 256, 0, stream>>>(x, Wm, masses);
  invdist_kernel<<<dim3(SEQ / 64, SEQ / 64), 256, 0, stream>>>(pos, invd);
  attn_mfma_kernel<<<dim3(BATCH * NHEAD, SEQ / 32), 256, 0, stream>>>(
      xt, masses, invd, G, attnout);
  out_gemm_mfma<<<dim3(DMODEL / 64, (BATCH * SEQ) / 64), 256, 0, stream>>>(
      attnout, wh, out);
}